// Round 1
// baseline (474.949 us; speedup 1.0000x reference)
//
#include <hip/hip_runtime.h>
#include <hip/hip_bf16.h>

typedef unsigned short u16;
typedef unsigned int u32;
typedef __attribute__((ext_vector_type(4))) float f32x4;
typedef __attribute__((ext_vector_type(8))) short bf16x8;

#define NUM_CAT 26
#define CARD 100000
#define NUM_NUM 13
#define EMBED 32
#define H1DIM 512
#define H2DIM 256
#define BATCH 16384
#define KCAT 832   // 26*32, deep-input K after folding constant num part into bias

__device__ __forceinline__ u16 f2bf(float f) {
    u32 u = __float_as_uint(f);
    u += 0x7fffu + ((u >> 16) & 1u);
    return (u16)(u >> 16);
}
__device__ __forceinline__ float bf2f(u16 u) {
    return __uint_as_float(((u32)u) << 16);
}

__device__ __forceinline__ void gload_lds16(const void* g, void* l) {
    __builtin_amdgcn_global_load_lds(
        (const __attribute__((address_space(1))) u32*)g,
        (__attribute__((address_space(3))) u32*)l, 16, 0, 0);
}

// ---------------------------------------------------------------------------
// prep: W1[:, :832] -> bf16; c1[j] = b1[j] + dot(W1[j, 832:], fm_num_flat);
//       W2 -> bf16
// grid 768 x 256
// ---------------------------------------------------------------------------
__global__ __launch_bounds__(256) void prep_kernel(
    const float* __restrict__ W1, const float* __restrict__ b1,
    const float* __restrict__ W2, const float* __restrict__ fm_num,
    u16* __restrict__ W1b, u16* __restrict__ W2b, float* __restrict__ c1)
{
    __shared__ float red[4];
    int j = blockIdx.x;
    int t = threadIdx.x;
    if (j < H1DIM) {
        const float* row = W1 + (size_t)j * 1248;
        for (int k = t; k < KCAT; k += 256)
            W1b[(size_t)j * KCAT + k] = f2bf(row[k]);
        float p = 0.f;
        for (int k = KCAT + t; k < 1248; k += 256)
            p += row[k] * fm_num[k - KCAT];
        #pragma unroll
        for (int off = 32; off >= 1; off >>= 1)
            p += __shfl_xor(p, off);
        if ((t & 63) == 0) red[t >> 6] = p;
        __syncthreads();
        if (t == 0) c1[j] = b1[j] + red[0] + red[1] + red[2] + red[3];
    } else {
        int r = j - H1DIM;  // 0..255
        const float* row = W2 + (size_t)r * H1DIM;
        for (int k = t; k < H1DIM; k += 256)
            W2b[(size_t)r * H1DIM + k] = f2bf(row[k]);
    }
}

// ---------------------------------------------------------------------------
// gather: per sample, gather cat embeddings, compute lin + FM, write X (bf16)
// one wave per sample; lanes 0-31 = even fields, 32-63 = odd fields
// grid 4096 x 256 (4 samples/block)
// ---------------------------------------------------------------------------
__global__ __launch_bounds__(256) void gather_kernel(
    const int* __restrict__ cat_x, const float* __restrict__ num_x,
    const float* __restrict__ lin_cat, const float* __restrict__ lin_num_w,
    const float* __restrict__ lin_bias, const float* __restrict__ fm_cat,
    const float* __restrict__ fm_num, const float* __restrict__ bo,
    u16* __restrict__ X, float* __restrict__ partial)
{
    int b = blockIdx.x * 4 + (threadIdx.x >> 6);
    int lane = threadIdx.x & 63;
    int e = lane & 31;
    int half = lane >> 5;
    const int* ci = cat_x + (size_t)b * NUM_CAT;

    float s = 0.f, ss = 0.f, lin = 0.f;
    #pragma unroll
    for (int i = 0; i < 13; i++) {
        int f = 2 * i + half;
        int idx = ci[f];
        size_t base = (size_t)f * CARD + idx;
        float v = fm_cat[base * EMBED + e];
        s += v;
        ss += v * v;
        if (e == 0) lin += lin_cat[base];
        X[(size_t)b * KCAT + f * EMBED + e] = f2bf(v);
    }
    // numeric fields: values = fm_num[f] * num_x[b,f]
    for (int tt = half; tt < NUM_NUM; tt += 2) {
        float v = fm_num[tt * EMBED + e] * num_x[b * NUM_NUM + tt];
        s += v;
        ss += v * v;
    }
    if (lane == 0) {
        float l2 = 0.f;
        #pragma unroll
        for (int jj = 0; jj < NUM_NUM; jj++)
            l2 += num_x[b * NUM_NUM + jj] * lin_num_w[jj];
        lin += l2 + lin_bias[0];
    }
    // combine even/odd halves
    s  += __shfl_xor(s, 32);
    ss += __shfl_xor(ss, 32);
    float val = s * s - ss;
    #pragma unroll
    for (int off = 16; off >= 1; off >>= 1)
        val += __shfl_xor(val, off);
    float fm = 0.5f * val;
    float lintot = lin + __shfl_xor(lin, 32);
    if (lane == 0) partial[b] = lintot + fm + bo[0];
}

// ---------------------------------------------------------------------------
// GEMM: C = relu(A @ Bm^T + bias), all bf16 except fp32 bias/acc.
// A: M x K (row-major bf16), Bm: N_DIM x K (row-major bf16), C: M x N_DIM bf16
// 128x128 tile, BK=32, 256 threads (4 waves, each 64x64 = 4x4 MFMA frags)
// m97 structure: global_load_lds width 16, 2 barriers per K-step.
// ---------------------------------------------------------------------------
template <int N_DIM>
__global__ __launch_bounds__(256) void gemm_relu_kernel(
    const u16* __restrict__ A, const u16* __restrict__ Bm,
    const float* __restrict__ bias, u16* __restrict__ C, int K)
{
    __shared__ u16 As[128 * 32];
    __shared__ u16 Bs[128 * 32];
    constexpr int nTilesN = N_DIM / 128;
    int bid = blockIdx.x;
    int tm = bid / nTilesN, tn = bid % nTilesN;
    int m0 = tm * 128, n0 = tn * 128;
    int t = threadIdx.x;
    int wave = t >> 6, lane = t & 63;
    int wr = wave >> 1, wc = wave & 1;
    int lr = lane & 15;   // fragment row (A) / col (B)
    int lk = lane >> 4;   // k-subgroup 0..3

    f32x4 acc[4][4] = {};

    int srow = t >> 2;          // 0..63
    int sseg = (t & 3) * 8;     // k element offset within 32 (x8 elems = 16B)

    for (int k0 = 0; k0 < K; k0 += 32) {
        // stage A,B tiles (128x32 bf16 each) via async global->LDS, 16B/lane
        gload_lds16(A + (size_t)(m0 + srow) * K + k0 + sseg, &As[t * 8]);
        gload_lds16(A + (size_t)(m0 + 64 + srow) * K + k0 + sseg, &As[2048 + t * 8]);
        gload_lds16(Bm + (size_t)(n0 + srow) * K + k0 + sseg, &Bs[t * 8]);
        gload_lds16(Bm + (size_t)(n0 + 64 + srow) * K + k0 + sseg, &Bs[2048 + t * 8]);
        __syncthreads();  // compiler drains vmcnt before barrier -> tiles ready

        bf16x8 af[4], bfr[4];
        #pragma unroll
        for (int m = 0; m < 4; m++)
            af[m] = *(const bf16x8*)&As[(wr * 64 + m * 16 + lr) * 32 + lk * 8];
        #pragma unroll
        for (int n = 0; n < 4; n++)
            bfr[n] = *(const bf16x8*)&Bs[(wc * 64 + n * 16 + lr) * 32 + lk * 8];
        #pragma unroll
        for (int m = 0; m < 4; m++)
            #pragma unroll
            for (int n = 0; n < 4; n++)
                acc[m][n] = __builtin_amdgcn_mfma_f32_16x16x32_bf16(
                    af[m], bfr[n], acc[m][n], 0, 0, 0);
        __syncthreads();  // all reads done before next-iter staging overwrites
    }

    // epilogue: bias + relu + bf16 store
    // C/D layout: col = lane&15, row = (lane>>4)*4 + i
    #pragma unroll
    for (int m = 0; m < 4; m++) {
        int row = m0 + wr * 64 + m * 16 + lk * 4;
        #pragma unroll
        for (int n = 0; n < 4; n++) {
            int col = n0 + wc * 64 + n * 16 + lr;
            float bv = bias[col];
            #pragma unroll
            for (int i = 0; i < 4; i++) {
                float v = acc[m][n][i] + bv;
                v = v > 0.f ? v : 0.f;
                C[(size_t)(row + i) * N_DIM + col] = f2bf(v);
            }
        }
    }
}

// ---------------------------------------------------------------------------
// final: out[b] = partial[b] + dot(H2[b, :], Wo)   (bo already in partial)
// one wave per sample, 4 bf16 per lane
// ---------------------------------------------------------------------------
__global__ __launch_bounds__(256) void final_kernel(
    const u16* __restrict__ H2, const float* __restrict__ Wo,
    const float* __restrict__ partial, float* __restrict__ out)
{
    int b = blockIdx.x * 4 + (threadIdx.x >> 6);
    int lane = threadIdx.x & 63;
    const u16* h = H2 + (size_t)b * H2DIM + lane * 4;
    ushort2 h01 = *(const ushort2*)h;
    ushort2 h23 = *(const ushort2*)(h + 2);
    float d = bf2f(h01.x) * Wo[lane * 4 + 0]
            + bf2f(h01.y) * Wo[lane * 4 + 1]
            + bf2f(h23.x) * Wo[lane * 4 + 2]
            + bf2f(h23.y) * Wo[lane * 4 + 3];
    #pragma unroll
    for (int off = 32; off >= 1; off >>= 1)
        d += __shfl_xor(d, off);
    if (lane == 0) out[b] = partial[b] + d;
}

// ---------------------------------------------------------------------------
extern "C" void kernel_launch(void* const* d_in, const int* in_sizes, int n_in,
                              void* d_out, int out_size, void* d_ws, size_t ws_size,
                              hipStream_t stream) {
    const int*   cat_x     = (const int*)d_in[0];
    const float* num_x     = (const float*)d_in[1];
    const float* lin_cat   = (const float*)d_in[2];
    const float* lin_num_w = (const float*)d_in[3];
    const float* lin_bias  = (const float*)d_in[4];
    const float* fm_cat    = (const float*)d_in[5];
    const float* fm_num    = (const float*)d_in[6];
    const float* W1        = (const float*)d_in[7];
    const float* b1        = (const float*)d_in[8];
    const float* W2        = (const float*)d_in[9];
    const float* b2        = (const float*)d_in[10];
    const float* Wo        = (const float*)d_in[11];
    const float* bo        = (const float*)d_in[12];
    float* out = (float*)d_out;

    char* ws = (char*)d_ws;
    u16*   X    = (u16*)(ws);                         // 16384*832*2   = 27,262,976
    u16*   W1b  = (u16*)(ws + 27262976);              // 512*832*2     =    851,968
    u16*   W2b  = (u16*)(ws + 28114944);              // 256*512*2     =    262,144
    float* c1   = (float*)(ws + 28377088);            // 512*4         =      2,048
    float* part = (float*)(ws + 28379136);            // 16384*4       =     65,536
    u16*   H1   = (u16*)(ws + 28444672);              // 16384*512*2   = 16,777,216
    u16*   H2   = (u16*)(ws + 45221888);              // 16384*256*2   =  8,388,608
    // total ws use: 53,610,496 bytes

    prep_kernel<<<768, 256, 0, stream>>>(W1, b1, W2, fm_num, W1b, W2b, c1);
    gather_kernel<<<BATCH / 4, 256, 0, stream>>>(cat_x, num_x, lin_cat, lin_num_w,
                                                 lin_bias, fm_cat, fm_num, bo, X, part);
    gemm_relu_kernel<H1DIM><<<(BATCH / 128) * (H1DIM / 128), 256, 0, stream>>>(
        X, W1b, c1, H1, KCAT);
    gemm_relu_kernel<H2DIM><<<(BATCH / 128) * (H2DIM / 128), 256, 0, stream>>>(
        H1, W2b, b2, H2, H1DIM);
    final_kernel<<<BATCH / 4, 256, 0, stream>>>(H2, Wo, part, out);
}